// Round 5
// baseline (236.906 us; speedup 1.0000x reference)
//
#include <hip/hip_runtime.h>
#include <math.h>

#define B_  4
#define CI  8
#define HH  128
#define WW  128
#define CO  16
#define KH  5
#define KW  5
#define HO  124
#define WO  124

#define TX  32
#define TY  8
#define THREADS 512   // 8 tx-groups * 8 rows * 8 waves; each wave owns ONE o

__global__ __launch_bounds__(THREADS, 4)
void maxplus_conv5(const float* __restrict__ img,
                   const float* __restrict__ kern,
                   float* __restrict__ out)
{
    // img tile rows y0..y0+11, cols x0..x0+35, -INF padded. [8][12][36] = 13.8 KB
    __shared__ __align__(16) float ilds[CI][TY + KH - 1][TX + KW - 1];

    const int tid   = threadIdx.x;
    const int x0    = blockIdx.x * TX;
    const int y0    = blockIdx.y * TY;
    const int bz    = blockIdx.z;        // b*2 + ohalf
    const int b     = bz >> 1;
    const int ohalf = bz & 1;

    // ---- stage img tile as float4 chunks: 8c * 12r * 9 float4 = 864 ----
    const float* imgb = img + (size_t)b * CI * HH * WW;
    #pragma unroll
    for (int it = 0; it < 2; ++it) {
        const int idx = tid + it * THREADS;
        if (idx < 864) {
            const int c   = idx / 108;
            const int rem = idx - c * 108;
            const int r   = rem / 9;
            const int f4  = rem - r * 9;
            const int gy = y0 + r;
            const int gx = x0 + f4 * 4;
            float4 v;
            if (gy < HH && gx < WW) {
                v = *(const float4*)&imgb[(c * HH + gy) * WW + gx];
            } else {
                v.x = v.y = v.z = v.w = -INFINITY;
            }
            *(float4*)&ilds[c][r][f4 * 4] = v;
        }
    }
    __syncthreads();

    const int tx = tid & 7;          // 4 px each
    const int ty = (tid >> 3) & 7;   // output row
    // one wave-uniform output channel per wave
    const int o = __builtin_amdgcn_readfirstlane(ohalf * 8 + (tid >> 6));

    const float* wp = kern + (size_t)o * (CI * KH * KW);

    float acc[4];
    #pragma unroll
    for (int p = 0; p < 4; ++p) acc[p] = -INFINITY;

    // FULL unroll: lets the scheduler issue c+1's s_loads/ds_reads under
    // c's VALU burst instead of convoy-stalling all waves at one lgkm drain.
    #pragma unroll
    for (int c = 0; c < CI; ++c) {
        // this channel's 25 weights, pre-flipped (uniform -> clustered s_load)
        float w[25];
        #pragma unroll
        for (int t = 0; t < 25; ++t) w[t] = wp[c * 25 + (24 - t)];  // w[i*5+j] = tap(4-i,4-j)
        // this channel's img window (10 ds_read_b128)
        float4 va[5], vb[5];
        #pragma unroll
        for (int i = 0; i < KH; ++i) {
            const float* vp = &ilds[c][ty + i][tx * 4];
            va[i] = *(const float4*)vp;
            vb[i] = *(const float4*)(vp + 4);
        }
        // pure-VALU compute: per (i,p): 5 add + 2 max3 + 1 max
        #pragma unroll
        for (int i = 0; i < KH; ++i) {
            const float v[8] = {va[i].x, va[i].y, va[i].z, va[i].w,
                                vb[i].x, vb[i].y, vb[i].z, vb[i].w};
            #pragma unroll
            for (int p = 0; p < 4; ++p) {
                float T[5];
                #pragma unroll
                for (int j = 0; j < KW; ++j) {
                    T[j] = v[p + j] + w[i * 5 + j];
                }
                const float m0 = fmaxf(fmaxf(acc[p], T[0]), T[1]);  // v_max3
                const float m1 = fmaxf(fmaxf(T[2], T[3]), T[4]);    // v_max3
                acc[p] = fmaxf(m0, m1);
            }
        }
    }

    // ---- write out: one float4 ----
    const int y = y0 + ty;
    const int x = x0 + tx * 4;
    if (y < HO && x < WO) {
        float4 s;
        s.x = acc[0]; s.y = acc[1]; s.z = acc[2]; s.w = acc[3];
        *(float4*)&out[(((size_t)b * CO + o) * HO + y) * WO + x] = s;
    }
}

extern "C" void kernel_launch(void* const* d_in, const int* in_sizes, int n_in,
                              void* d_out, int out_size, void* d_ws, size_t ws_size,
                              hipStream_t stream)
{
    const float* img  = (const float*)d_in[0];
    const float* kern = (const float*)d_in[1];
    float* out = (float*)d_out;

    dim3 grid((WO + TX - 1) / TX, (HO + TY - 1) / TY, B_ * 2);  // 4 x 16 x 8 = 512 blocks
    dim3 block(THREADS);
    maxplus_conv5<<<grid, block, 0, stream>>>(img, kern, out);
}

// Round 6
// 18.593 us; speedup vs baseline: 12.7416x; 12.7416x over previous
//
#include <hip/hip_runtime.h>
#include <math.h>

#define B_  4
#define CI  8
#define HH  128
#define WW  128
#define CO  16
#define KH  5
#define KW  5
#define HO  124
#define WO  124

#define TX  32
#define TY  8
#define THREADS 256   // 4 waves; each wave owns an o-pair within its z-half

using f32x2 = __attribute__((ext_vector_type(2))) float;

__global__ __launch_bounds__(THREADS)
void maxplus_conv6(const float* __restrict__ img,
                   const float* __restrict__ kern,
                   float* __restrict__ out)
{
    // img tile rows y0..y0+11, cols x0..x0+35, -INF padded. [8][12][36] = 13.8 KB
    __shared__ __align__(16) float ilds[CI][TY + KH - 1][TX + KW - 1];

    const int tid   = threadIdx.x;
    const int x0    = blockIdx.x * TX;
    const int y0    = blockIdx.y * TY;
    const int bz    = blockIdx.z;        // b*2 + ohalf
    const int b     = bz >> 1;
    const int ohalf = bz & 1;

    // ---- stage img tile as float4 chunks: 8c * 12r * 9 f4 = 864 ----
    const float* imgb = img + (size_t)b * CI * HH * WW;
    #pragma unroll
    for (int it = 0; it < 4; ++it) {
        const int idx = tid + it * THREADS;
        if (idx < 864) {
            const int c   = idx / 108;
            const int rem = idx - c * 108;
            const int r   = rem / 9;
            const int f4  = rem - r * 9;
            const int gy = y0 + r, gx = x0 + f4 * 4;
            float4 v;
            if (gy < HH && gx < WW) v = *(const float4*)&imgb[(c * HH + gy) * WW + gx];
            else { v.x = v.y = v.z = v.w = -INFINITY; }
            *(float4*)&ilds[c][r][f4 * 4] = v;
        }
    }
    __syncthreads();

    const int tx = tid & 7;          // 4 px each
    const int ty = (tid >> 3) & 7;   // output row
    // wave-uniform o-pair
    const int o0 = __builtin_amdgcn_readfirstlane(ohalf * 8 + ((tid >> 6) << 1));

    const float* w0p = kern + (size_t)o0 * (CI * KH * KW);
    const float* w1p = w0p + CI * KH * KW;

    float accx[4], accy[4];
    #pragma unroll
    for (int p = 0; p < 4; ++p) { accx[p] = -INFINITY; accy[p] = -INFINITY; }

    // 2-deep software pipeline: static A/B buffers (no runtime indexing -> no scratch)
    float4 vaA[5], vbA[5], vaB[5], vbB[5];
    f32x2 WA[25], WB[25];

#define PREF_IMG(S, c) do { \
    _Pragma("unroll") \
    for (int i = 0; i < KH; ++i) { \
        const float* vp = &ilds[c][ty + i][tx * 4]; \
        va##S[i] = *(const float4*)vp; \
        vb##S[i] = *(const float4*)(vp + 4); \
    } } while (0)

    // pre-flipped weight pairs: W[t] = {kern_o0, kern_o1} at tap index t=i*5+j <-> (4-i,4-j)
#define PREF_W(S, c) do { \
    _Pragma("unroll") \
    for (int t = 0; t < 25; ++t) { \
        W##S[t].x = w0p[(c) * 25 + (24 - t)]; \
        W##S[t].y = w1p[(c) * 25 + (24 - t)]; \
    } } while (0)

    // per (i,p): 5 v_pk_add_f32 (2 adds each, o-pair packed) + 2 max3 + ... = 11 VALU / 2 outputs
#define COMP(S) do { \
    _Pragma("unroll") \
    for (int i = 0; i < KH; ++i) { \
        const float vv[8] = {va##S[i].x, va##S[i].y, va##S[i].z, va##S[i].w, \
                             vb##S[i].x, vb##S[i].y, vb##S[i].z, vb##S[i].w}; \
        _Pragma("unroll") \
        for (int p = 0; p < 4; ++p) { \
            f32x2 t0 = (f32x2){vv[p + 0], vv[p + 0]} + W##S[i * 5 + 0]; \
            f32x2 t1 = (f32x2){vv[p + 1], vv[p + 1]} + W##S[i * 5 + 1]; \
            f32x2 t2 = (f32x2){vv[p + 2], vv[p + 2]} + W##S[i * 5 + 2]; \
            f32x2 t3 = (f32x2){vv[p + 3], vv[p + 3]} + W##S[i * 5 + 3]; \
            f32x2 t4 = (f32x2){vv[p + 4], vv[p + 4]} + W##S[i * 5 + 4]; \
            accx[p] = fmaxf(fmaxf(fmaxf(accx[p], t0.x), t1.x), \
                            fmaxf(fmaxf(t2.x, t3.x), t4.x)); \
            accy[p] = fmaxf(fmaxf(fmaxf(accy[p], t0.y), t1.y), \
                            fmaxf(fmaxf(t2.y, t3.y), t4.y)); \
        } \
    } } while (0)

    PREF_IMG(A, 0);
    PREF_W(A, 0);
    #pragma unroll 1
    for (int cp = 0; cp < CI / 2; ++cp) {
        const int c0 = cp * 2;
        PREF_IMG(B, c0 + 1);
        PREF_W(B, c0 + 1);
        COMP(A);
        if (cp < CI / 2 - 1) {       // uniform branch
            PREF_IMG(A, c0 + 2);
            PREF_W(A, c0 + 2);
        }
        COMP(B);
    }

    // ---- write out: one float4 per o ----
    const int y = y0 + ty;
    const int x = x0 + tx * 4;
    if (y < HO && x < WO) {
        float4 s0, s1;
        s0.x = accx[0]; s0.y = accx[1]; s0.z = accx[2]; s0.w = accx[3];
        s1.x = accy[0]; s1.y = accy[1]; s1.z = accy[2]; s1.w = accy[3];
        *(float4*)&out[(((size_t)b * CO + o0) * HO + y) * WO + x] = s0;
        *(float4*)&out[(((size_t)b * CO + o0 + 1) * HO + y) * WO + x] = s1;
    }
}

extern "C" void kernel_launch(void* const* d_in, const int* in_sizes, int n_in,
                              void* d_out, int out_size, void* d_ws, size_t ws_size,
                              hipStream_t stream)
{
    const float* img  = (const float*)d_in[0];
    const float* kern = (const float*)d_in[1];
    float* out = (float*)d_out;

    dim3 grid((WO + TX - 1) / TX, (HO + TY - 1) / TY, B_ * 2);  // 4 x 16 x 8 = 512 blocks
    dim3 block(THREADS);
    maxplus_conv6<<<grid, block, 0, stream>>>(img, kern, out);
}